// Round 8
// baseline (193.233 us; speedup 1.0000x reference)
//
#include <hip/hip_runtime.h>
#include <math.h>

// Tropical max-plus conv, f32.
// imgs (4,32,128,128), kernel (32,32,5,5) flipped, stride=1, pad=2, dil=1.
// out (4,32,128,128).
//
// Decomposition: block = 256 threads (ty=8 x tx=32), each thread computes
// O_TILE=4 outputs x X_TILE=4 consecutive x -> 16 accumulators.
// Block covers: 1 batch, 4 output channels, 8 rows, full 128 width.
// Grid = 4b * 8ob * 16yb = 512 blocks -> 2 blocks/CU, 8 waves/CU.

#define TY 8
#define PITCH 132      // 128 + 4 halo (dwords); 132*4B % 16 == 0 -> b128-aligned
#define ROWS 12        // TY + 4

__global__ __launch_bounds__(256, 2)
void tropical_conv_kernel(const float* __restrict__ img,
                          const float* __restrict__ ker,
                          float* __restrict__ out) {
    const int bid = blockIdx.x;
    const int yb = bid & 15;         // 16 y-tiles
    const int ob = (bid >> 4) & 7;   // 8 o-tiles (4 o each)
    const int b  = bid >> 7;         // 4 batches
    const int y0 = yb * TY;
    const int obase = ob * 4;

    const int tid = threadIdx.x;
    const int tx = tid & 31;   // 32 x-threads, 4 outputs each -> 128 wide
    const int ty = tid >> 5;   // 8 y rows

    __shared__ __align__(16) float s_k[32 * 5 * 5 * 4]; // [c][i][j][oo], flipped
    __shared__ __align__(16) float s_img[ROWS * PITCH];

    // Stage flipped kernel slice for this block's 4 output channels (once).
    for (int idx = tid; idx < 3200; idx += 256) {
        int oo = idx & 3;
        int r = idx >> 2;
        int j = r % 5; r /= 5;
        int i = r % 5;
        int c = r / 5;
        s_k[idx] = ker[(obase + oo) * 800 + c * 25 + (4 - i) * 5 + (4 - j)];
    }

    float acc[4][4];
    #pragma unroll
    for (int o = 0; o < 4; ++o)
        #pragma unroll
        for (int xx = 0; xx < 4; ++xx)
            acc[o][xx] = -INFINITY;

    const float* imgb = img + (size_t)b * 32 * 128 * 128;

    for (int c = 0; c < 32; ++c) {
        __syncthreads();   // also covers s_k staging before first use
        const float* imgc = imgb + (size_t)c * 128 * 128;
        // Stage 12 x 132 halo tile (pad = -inf outside the image).
        for (int idx = tid; idx < ROWS * PITCH; idx += 256) {
            int row = idx / PITCH;
            int col = idx - row * PITCH;
            int gy = y0 + row - 2;
            int gx = col - 2;
            float v = -INFINITY;
            if ((unsigned)gy < 128u && (unsigned)gx < 128u)
                v = imgc[gy * 128 + gx];
            s_img[idx] = v;
        }
        __syncthreads();

        #pragma unroll
        for (int i = 0; i < 5; ++i) {
            // 8 consecutive image values serve all 5 kernel-x positions
            // for this thread's 4 outputs (sliding window).
            const float4 r0 = *(const float4*)&s_img[(ty + i) * PITCH + tx * 4];
            const float4 r1 = *(const float4*)&s_img[(ty + i) * PITCH + tx * 4 + 4];
            const float r[8] = {r0.x, r0.y, r0.z, r0.w, r1.x, r1.y, r1.z, r1.w};
            const float4* kw = (const float4*)&s_k[(c * 25 + i * 5) * 4];

            // j in pairs -> fmax(fmax(acc, a), b) folds to v_max3_f32.
            #pragma unroll
            for (int jp = 0; jp < 2; ++jp) {
                float4 w0 = kw[2 * jp];
                float4 w1 = kw[2 * jp + 1];
                const float wa0[4] = {w0.x, w0.y, w0.z, w0.w};
                const float wa1[4] = {w1.x, w1.y, w1.z, w1.w};
                #pragma unroll
                for (int o = 0; o < 4; ++o)
                    #pragma unroll
                    for (int xx = 0; xx < 4; ++xx)
                        acc[o][xx] = fmaxf(fmaxf(acc[o][xx],
                                                 r[2 * jp + xx] + wa0[o]),
                                           r[2 * jp + 1 + xx] + wa1[o]);
            }
            {
                float4 w4 = kw[4];
                const float wa[4] = {w4.x, w4.y, w4.z, w4.w};
                #pragma unroll
                for (int o = 0; o < 4; ++o)
                    #pragma unroll
                    for (int xx = 0; xx < 4; ++xx)
                        acc[o][xx] = fmaxf(acc[o][xx], r[4 + xx] + wa[o]);
            }
        }
    }

    // Write 4 output channels x 4 consecutive x as float4 stores.
    #pragma unroll
    for (int o = 0; o < 4; ++o) {
        float4 v = make_float4(acc[o][0], acc[o][1], acc[o][2], acc[o][3]);
        *(float4*)&out[((size_t)(b * 32 + obase + o) * 128 + y0 + ty) * 128 + tx * 4] = v;
    }
}

extern "C" void kernel_launch(void* const* d_in, const int* in_sizes, int n_in,
                              void* d_out, int out_size, void* d_ws, size_t ws_size,
                              hipStream_t stream) {
    const float* img = (const float*)d_in[0];
    const float* ker = (const float*)d_in[1];
    float* out = (float*)d_out;
    tropical_conv_kernel<<<512, 256, 0, stream>>>(img, ker, out);
}

// Round 13
// 154.970 us; speedup vs baseline: 1.2469x; 1.2469x over previous
//
#include <hip/hip_runtime.h>
#include <math.h>

// Tropical max-plus conv, f32. imgs (4,32,128,128), kernel (32,32,5,5)
// flipped, stride=1, pad=2, dil=1. out (4,32,128,128).
//
// R8 counters: dur 150us, VALUBusy 53%, bank-conflict 0, HBM 1.2%.
// Diagnosis: staging latency on critical path (serial global loads between
// two barriers/channel) + 25 uniform-address LDS weight reads per channel.
// This round: reg-prefetch + LDS dbuf (1 barrier/channel), hoisted
// channel-invariant staging offsets, weights via scalar loads (SGPR path).

#define TY 8
#define PITCH 132      // 128 + 4 halo (dwords); row = 528 B = 33*16 -> b128-aligned
#define ROWS 12        // TY + 4
#define TILE (ROWS * PITCH)   // 1584 dwords
#define NSLOT 7               // ceil(TILE/256)

__global__ __launch_bounds__(256, 2)
void tropical_conv_kernel(const float* __restrict__ img,
                          const float* __restrict__ ker,
                          float* __restrict__ out) {
    const int bid = blockIdx.x;
    const int yb = bid & 15;         // 16 y-tiles
    const int ob = (bid >> 4) & 7;   // 8 o-tiles (4 o each)
    const int b  = bid >> 7;         // 4 batches
    const int y0 = yb * TY;
    const int obase = ob * 4;

    const int tid = threadIdx.x;
    const int tx = tid & 31;   // 32 x-threads, 4 outputs each
    const int ty = tid >> 5;   // 8 y rows

    __shared__ __align__(16) float s_img[2][TILE];

    // Channel-invariant staging geometry (computed once, not 32x).
    // Slot k <-> LDS index tid + 256k. goff = dword offset in channel plane.
    int goff[NSLOT];
    #pragma unroll
    for (int k = 0; k < NSLOT; ++k) {
        int idx = tid + k * 256;
        int row = idx / PITCH;
        int col = idx - row * PITCH;
        int gy = y0 + row - 2;
        int gx = col - 2;
        bool slot = idx < TILE;
        bool ok = slot && ((unsigned)gy < 128u) && ((unsigned)gx < 128u);
        goff[k] = ok ? (gy * 128 + gx) : -1;
        // Halo slots are channel-invariant: write -inf once to both buffers.
        if (slot && !ok) {
            s_img[0][idx] = -INFINITY;
            s_img[1][idx] = -INFINITY;
        }
    }

    const float* imgb = img + (size_t)b * (32 * 128 * 128);

    float acc[4][4];
    #pragma unroll
    for (int o = 0; o < 4; ++o)
        #pragma unroll
        for (int xx = 0; xx < 4; ++xx)
            acc[o][xx] = -INFINITY;

    // Prologue: stage channel 0 into buffer 0.
    float rbuf[NSLOT];
    #pragma unroll
    for (int k = 0; k < NSLOT; ++k)
        if (goff[k] >= 0) rbuf[k] = imgb[goff[k]];
    #pragma unroll
    for (int k = 0; k < NSLOT; ++k)
        if (goff[k] >= 0) s_img[0][tid + k * 256] = rbuf[k];
    __syncthreads();

    int p = 0;
    for (int c = 0; c < 32; ++c) {
        // Prefetch channel c+1 into registers; latency hides under compute.
        if (c < 31) {
            const float* imgc = imgb + ((c + 1) << 14);
            #pragma unroll
            for (int k = 0; k < NSLOT; ++k)
                if (goff[k] >= 0) rbuf[k] = imgc[goff[k]];
        }

        const float* srow = s_img[p];
        #pragma unroll
        for (int i = 0; i < 5; ++i) {
            const float4 r0 = *(const float4*)&srow[(ty + i) * PITCH + tx * 4];
            const float4 r1 = *(const float4*)&srow[(ty + i) * PITCH + tx * 4 + 4];
            const float r[8] = {r0.x, r0.y, r0.z, r0.w, r1.x, r1.y, r1.z, r1.w};

            // Weights: wave-uniform addresses -> scalar loads (SGPR operands).
            // w[j][o] = k_flipped[obase+o][c][i][j]
            float w[5][4];
            #pragma unroll
            for (int o = 0; o < 4; ++o) {
                const float* kr = ker + (obase + o) * 800 + c * 25 + (4 - i) * 5;
                #pragma unroll
                for (int j = 0; j < 5; ++j)
                    w[j][o] = kr[4 - j];
            }

            // j in pairs -> fmax(fmax(acc, a), b) folds to v_max3_f32.
            #pragma unroll
            for (int jp = 0; jp < 2; ++jp) {
                #pragma unroll
                for (int o = 0; o < 4; ++o)
                    #pragma unroll
                    for (int xx = 0; xx < 4; ++xx)
                        acc[o][xx] = fmaxf(fmaxf(acc[o][xx],
                                                 r[2 * jp + xx] + w[2 * jp][o]),
                                           r[2 * jp + 1 + xx] + w[2 * jp + 1][o]);
            }
            #pragma unroll
            for (int o = 0; o < 4; ++o)
                #pragma unroll
                for (int xx = 0; xx < 4; ++xx)
                    acc[o][xx] = fmaxf(acc[o][xx], r[4 + xx] + w[4][o]);
        }

        // Stage c+1 into the other buffer (no reader conflict), one barrier.
        if (c < 31) {
            #pragma unroll
            for (int k = 0; k < NSLOT; ++k)
                if (goff[k] >= 0) s_img[p ^ 1][tid + k * 256] = rbuf[k];
        }
        __syncthreads();
        p ^= 1;
    }

    // Write 4 output channels x 4 consecutive x as float4 stores.
    #pragma unroll
    for (int o = 0; o < 4; ++o) {
        float4 v = make_float4(acc[o][0], acc[o][1], acc[o][2], acc[o][3]);
        *(float4*)&out[((size_t)(b * 32 + obase + o) * 128 + y0 + ty) * 128 + tx * 4] = v;
    }
}

extern "C" void kernel_launch(void* const* d_in, const int* in_sizes, int n_in,
                              void* d_out, int out_size, void* d_ws, size_t ws_size,
                              hipStream_t stream) {
    const float* img = (const float*)d_in[0];
    const float* ker = (const float*)d_in[1];
    float* out = (float*)d_out;
    tropical_conv_kernel<<<512, 256, 0, stream>>>(img, ker, out);
}

// Round 16
// 136.790 us; speedup vs baseline: 1.4126x; 1.1329x over previous
//
#include <hip/hip_runtime.h>
#include <math.h>

// Tropical max-plus conv, f32. imgs (4,32,128,128), kernel (32,32,5,5)
// flipped, stride=1, pad=2, dil=1. out (4,32,128,128).
//
// R13 counters: dur 101us, VALUBusy 71%, Occupancy 19% (grid 512 = 2
// blocks/CU, grid-limited), conflicts 0, VGPR 60.
// This round: TY=4, grid 1024 -> 4 blocks/CU, 16 waves/CU (~50% occ) to
// fill the 29% idle; per-thread tile 4o x 2x (8 accs). v_max3_f32 forced
// via inline asm (removes fusion uncertainty; adds stay compiler-sched).

#define TY 4
#define PITCH 132      // dwords; row = 528 B (16B-aligned rows)
#define ROWS 8         // TY + 4
#define TILE (ROWS * PITCH)   // 1056 dwords
#define NSLOT 5               // ceil(TILE/256)

__device__ __forceinline__ float max3f(float a, float b, float c) {
    float d;
    asm("v_max3_f32 %0, %1, %2, %3" : "=v"(d) : "v"(a), "v"(b), "v"(c));
    return d;
}

__global__ __launch_bounds__(256, 4)
void tropical_conv_kernel(const float* __restrict__ img,
                          const float* __restrict__ ker,
                          float* __restrict__ out) {
    const int bid = blockIdx.x;
    const int yb = bid & 31;         // 32 y-tiles (4 rows each)
    const int ob = (bid >> 5) & 7;   // 8 o-tiles (4 o each)
    const int b  = bid >> 8;         // 4 batches
    const int y0 = yb * TY;
    const int obase = ob * 4;

    const int tid = threadIdx.x;
    const int tx = tid & 63;   // 64 x-threads, 2 x each -> 128 wide
    const int ty = tid >> 6;   // 4 rows
    const int x0 = tx * 2;

    __shared__ __align__(16) float s_img[2][TILE];

    // Channel-invariant staging geometry. Slot k <-> LDS idx tid + 256k.
    int goff[NSLOT];
    #pragma unroll
    for (int k = 0; k < NSLOT; ++k) {
        int idx = tid + k * 256;
        int row = idx / PITCH;
        int col = idx - row * PITCH;
        int gy = y0 + row - 2;
        int gx = col - 2;
        bool slot = idx < TILE;
        bool ok = slot && ((unsigned)gy < 128u) && ((unsigned)gx < 128u);
        goff[k] = ok ? (gy * 128 + gx) : -1;
        // Halo slots are channel-invariant: -inf once, both buffers.
        if (slot && !ok) {
            s_img[0][idx] = -INFINITY;
            s_img[1][idx] = -INFINITY;
        }
    }

    const float* imgb = img + (size_t)b * (32 * 128 * 128);

    float acc[4][2];
    #pragma unroll
    for (int o = 0; o < 4; ++o) {
        acc[o][0] = -INFINITY;
        acc[o][1] = -INFINITY;
    }

    // Prologue: stage channel 0 into buffer 0.
    float rbuf[NSLOT];
    #pragma unroll
    for (int k = 0; k < NSLOT; ++k)
        if (goff[k] >= 0) rbuf[k] = imgb[goff[k]];
    #pragma unroll
    for (int k = 0; k < NSLOT; ++k)
        if (goff[k] >= 0) s_img[0][tid + k * 256] = rbuf[k];
    __syncthreads();

    int p = 0;
    for (int c = 0; c < 32; ++c) {
        // Prefetch channel c+1 into registers; hides under compute.
        if (c < 31) {
            const float* imgc = imgb + ((c + 1) << 14);
            #pragma unroll
            for (int k = 0; k < NSLOT; ++k)
                if (goff[k] >= 0) rbuf[k] = imgc[goff[k]];
        }

        const float* srow = s_img[p];
        #pragma unroll
        for (int i = 0; i < 5; ++i) {
            const float2 r01 = *(const float2*)&srow[(ty + i) * PITCH + x0];
            const float2 r23 = *(const float2*)&srow[(ty + i) * PITCH + x0 + 2];
            const float2 r45 = *(const float2*)&srow[(ty + i) * PITCH + x0 + 4];
            const float r[6] = {r01.x, r01.y, r23.x, r23.y, r45.x, r45.y};

            // Weights: wave-uniform addresses -> scalar loads.
            // w[j][o] = k_flipped[obase+o][c][i][j]
            float w[5][4];
            #pragma unroll
            for (int o = 0; o < 4; ++o) {
                const float* kr = ker + (obase + o) * 800 + c * 25 + (4 - i) * 5;
                #pragma unroll
                for (int j = 0; j < 5; ++j)
                    w[j][o] = kr[4 - j];
            }

            #pragma unroll
            for (int o = 0; o < 4; ++o)
                #pragma unroll
                for (int xx = 0; xx < 2; ++xx) {
                    float t0 = r[0 + xx] + w[0][o];
                    float t1 = r[1 + xx] + w[1][o];
                    acc[o][xx] = max3f(acc[o][xx], t0, t1);
                    float t2 = r[2 + xx] + w[2][o];
                    float t3 = r[3 + xx] + w[3][o];
                    acc[o][xx] = max3f(acc[o][xx], t2, t3);
                    acc[o][xx] = fmaxf(acc[o][xx], r[4 + xx] + w[4][o]);
                }
        }

        // Stage c+1 into the other buffer; single barrier per channel.
        if (c < 31) {
            #pragma unroll
            for (int k = 0; k < NSLOT; ++k)
                if (goff[k] >= 0) s_img[p ^ 1][tid + k * 256] = rbuf[k];
        }
        __syncthreads();
        p ^= 1;
    }

    // Write 4 output channels x 2 consecutive x as float2 stores.
    #pragma unroll
    for (int o = 0; o < 4; ++o) {
        float2 v = make_float2(acc[o][0], acc[o][1]);
        *(float2*)&out[((size_t)(b * 32 + obase + o) * 128 + y0 + ty) * 128 + x0] = v;
    }
}

extern "C" void kernel_launch(void* const* d_in, const int* in_sizes, int n_in,
                              void* d_out, int out_size, void* d_ws, size_t ws_size,
                              hipStream_t stream) {
    const float* img = (const float*)d_in[0];
    const float* ker = (const float*)d_in[1];
    float* out = (float*)d_out;
    tropical_conv_kernel<<<1024, 256, 0, stream>>>(img, ker, out);
}

// Round 19
// 135.714 us; speedup vs baseline: 1.4238x; 1.0079x over previous
//
#include <hip/hip_runtime.h>
#include <math.h>

// Tropical max-plus conv, f32. imgs (4,32,128,128), kernel (32,32,5,5)
// flipped, stride=1, pad=2, dil=1. out (4,32,128,128).
//
// R16: dur 85us, VALUBusy "94%" -- but gfx94x VALUBusy formula assumes
// 4cyc/instr (SIMD-16); gfx950 is SIMD-32 (2cyc). Real issue ~43us of 85
// -> ~50% util, stall-bound. Suspect: s_load weights (SMEM) mixed with
// ds_read in inner loop; SMEM is out-of-order on lgkmcnt -> forces
// lgkmcnt(0) full-queue drains every i-iteration.
// This round (single delta): weights staged ONCE into LDS (12.8KB,
// [c][i][j][o] o-contiguous), read as wave-uniform float4 broadcasts.
// Inner loop becomes DS-only -> in-order queue -> partial lgkmcnt waits.

#define TY 4
#define PITCH 132      // dwords; row = 528 B (16B-aligned rows)
#define ROWS 8         // TY + 4
#define TILE (ROWS * PITCH)   // 1056 dwords
#define NSLOT 5               // ceil(TILE/256)

__device__ __forceinline__ float max3f(float a, float b, float c) {
    float d;
    asm("v_max3_f32 %0, %1, %2, %3" : "=v"(d) : "v"(a), "v"(b), "v"(c));
    return d;
}

__global__ __launch_bounds__(256, 4)
void tropical_conv_kernel(const float* __restrict__ img,
                          const float* __restrict__ ker,
                          float* __restrict__ out) {
    const int bid = blockIdx.x;
    const int yb = bid & 31;         // 32 y-tiles (4 rows each)
    const int ob = (bid >> 5) & 7;   // 8 o-tiles (4 o each)
    const int b  = bid >> 8;         // 4 batches
    const int y0 = yb * TY;
    const int obase = ob * 4;

    const int tid = threadIdx.x;
    const int tx = tid & 63;   // 64 x-threads, 2 x each -> 128 wide
    const int ty = tid >> 6;   // 4 rows
    const int x0 = tx * 2;

    __shared__ __align__(16) float s_img[2][TILE];
    __shared__ __align__(16) float s_k[3200];   // [c][i][j][o], flipped

    // Stage flipped weights for this block's 4 o-channels (once).
    // Layout verified correct in R8 run (passed, absmax 0).
    for (int idx = tid; idx < 3200; idx += 256) {
        int o = idx & 3;
        int r = idx >> 2;
        int j = r % 5; r /= 5;
        int i = r % 5;
        int c = r / 5;
        s_k[idx] = ker[(obase + o) * 800 + c * 25 + (4 - i) * 5 + (4 - j)];
    }

    // Channel-invariant staging geometry. Slot k <-> LDS idx tid + 256k.
    int goff[NSLOT];
    #pragma unroll
    for (int k = 0; k < NSLOT; ++k) {
        int idx = tid + k * 256;
        int row = idx / PITCH;
        int col = idx - row * PITCH;
        int gy = y0 + row - 2;
        int gx = col - 2;
        bool slot = idx < TILE;
        bool ok = slot && ((unsigned)gy < 128u) && ((unsigned)gx < 128u);
        goff[k] = ok ? (gy * 128 + gx) : -1;
        // Halo slots are channel-invariant: -inf once, both buffers.
        if (slot && !ok) {
            s_img[0][idx] = -INFINITY;
            s_img[1][idx] = -INFINITY;
        }
    }

    const float* imgb = img + (size_t)b * (32 * 128 * 128);

    float acc[4][2];
    #pragma unroll
    for (int o = 0; o < 4; ++o) {
        acc[o][0] = -INFINITY;
        acc[o][1] = -INFINITY;
    }

    // Prologue: stage channel 0 into buffer 0 (barrier also covers s_k).
    float rbuf[NSLOT];
    #pragma unroll
    for (int k = 0; k < NSLOT; ++k)
        if (goff[k] >= 0) rbuf[k] = imgb[goff[k]];
    #pragma unroll
    for (int k = 0; k < NSLOT; ++k)
        if (goff[k] >= 0) s_img[0][tid + k * 256] = rbuf[k];
    __syncthreads();

    int p = 0;
    for (int c = 0; c < 32; ++c) {
        // Prefetch channel c+1 into registers; hides under compute.
        if (c < 31) {
            const float* imgc = imgb + ((c + 1) << 14);
            #pragma unroll
            for (int k = 0; k < NSLOT; ++k)
                if (goff[k] >= 0) rbuf[k] = imgc[goff[k]];
        }

        const float* srow = s_img[p];
        #pragma unroll
        for (int i = 0; i < 5; ++i) {
            const float2 r01 = *(const float2*)&srow[(ty + i) * PITCH + x0];
            const float2 r23 = *(const float2*)&srow[(ty + i) * PITCH + x0 + 2];
            const float2 r45 = *(const float2*)&srow[(ty + i) * PITCH + x0 + 4];
            const float r[6] = {r01.x, r01.y, r23.x, r23.y, r45.x, r45.y};

            // Weights from LDS: wave-uniform addr -> broadcast, no conflict.
            const float4* kw = (const float4*)&s_k[(c * 25 + i * 5) * 4];
            const float4 w0 = kw[0], w1 = kw[1], w2 = kw[2], w3 = kw[3],
                         w4 = kw[4];
            const float wa0[4] = {w0.x, w0.y, w0.z, w0.w};
            const float wa1[4] = {w1.x, w1.y, w1.z, w1.w};
            const float wa2[4] = {w2.x, w2.y, w2.z, w2.w};
            const float wa3[4] = {w3.x, w3.y, w3.z, w3.w};
            const float wa4[4] = {w4.x, w4.y, w4.z, w4.w};

            #pragma unroll
            for (int o = 0; o < 4; ++o)
                #pragma unroll
                for (int xx = 0; xx < 2; ++xx) {
                    float t0 = r[0 + xx] + wa0[o];
                    float t1 = r[1 + xx] + wa1[o];
                    acc[o][xx] = max3f(acc[o][xx], t0, t1);
                    float t2 = r[2 + xx] + wa2[o];
                    float t3 = r[3 + xx] + wa3[o];
                    acc[o][xx] = max3f(acc[o][xx], t2, t3);
                    acc[o][xx] = fmaxf(acc[o][xx], r[4 + xx] + wa4[o]);
                }
        }

        // Stage c+1 into the other buffer; single barrier per channel.
        if (c < 31) {
            #pragma unroll
            for (int k = 0; k < NSLOT; ++k)
                if (goff[k] >= 0) s_img[p ^ 1][tid + k * 256] = rbuf[k];
        }
        __syncthreads();
        p ^= 1;
    }

    // Write 4 output channels x 2 consecutive x as float2 stores.
    #pragma unroll
    for (int o = 0; o < 4; ++o) {
        float2 v = make_float2(acc[o][0], acc[o][1]);
        *(float2*)&out[((size_t)(b * 32 + obase + o) * 128 + y0 + ty) * 128 + x0] = v;
    }
}

extern "C" void kernel_launch(void* const* d_in, const int* in_sizes, int n_in,
                              void* d_out, int out_size, void* d_ws, size_t ws_size,
                              hipStream_t stream) {
    const float* img = (const float*)d_in[0];
    const float* ker = (const float*)d_in[1];
    float* out = (float*)d_out;
    tropical_conv_kernel<<<1024, 256, 0, stream>>>(img, ker, out);
}